// Round 3
// baseline (749.931 us; speedup 1.0000x reference)
//
#include <hip/hip_runtime.h>
#include <math.h>

#define N_NODES 50000
#define N_EDGES 800000
#define NUM_GRAPHS 256
#define C_IN 64
#define C_H 128
#define D_COUNT 9
#define LRELU_SLOPE 0.01f
#define BN_EPS 1e-5f
#define EBLK 256

__device__ __forceinline__ float fast_rcp(float x) { return __builtin_amdgcn_rcpf(x); }

// ---------------- CSR build (once; edge structure shared by all 3 layers) ------------------

__global__ void hist_kernel(const int* __restrict__ col, int* __restrict__ counts) {
    const int e = blockIdx.x * 256 + threadIdx.x;
    if (e < N_EDGES) atomicAdd(&counts[col[e]], 1);
}

__global__ void scan_kernel(const int* __restrict__ counts, int* __restrict__ offsets,
                            int* __restrict__ cur) {
    __shared__ int part[1024];
    const int t = threadIdx.x;
    const int CH = (N_NODES + 1023) / 1024;  // 49
    const int lo = t * CH;
    const int hi = min(lo + CH, N_NODES);
    int s = 0;
    for (int i = lo; i < hi; ++i) s += counts[i];
    part[t] = s;
    __syncthreads();
    for (int d = 1; d < 1024; d <<= 1) {
        int v = 0;
        if (t >= d) v = part[t - d];
        __syncthreads();
        part[t] += v;
        __syncthreads();
    }
    int base = (t == 0) ? 0 : part[t - 1];
    for (int i = lo; i < hi; ++i) {
        const int c = counts[i];
        offsets[i] = base;
        cur[i] = base;
        base += c;
    }
    if (t == 1023) offsets[N_NODES] = N_EDGES;
}

__global__ void scatter_kernel(const int* __restrict__ row, const int* __restrict__ col,
                               int* __restrict__ cur, int2* __restrict__ rc_csr) {
    const int e = blockIdx.x * 256 + threadIdx.x;
    if (e < N_EDGES) {
        const int cl = col[e];
        const int p = atomicAdd(&cur[cl], 1);
        rc_csr[p] = make_int2(row[e], cl);
    }
}

// ---------------- h = silu(x @ W_lin + b_lin) ----------------------------------------------
__global__ void lin0_kernel(const float* __restrict__ x, const float* __restrict__ W,
                            const float* __restrict__ b, float* __restrict__ h) {
    __shared__ float xs[8][C_IN];
    const int node0 = blockIdx.x * 8;
    const int t = threadIdx.x;
    for (int i = t; i < 8 * C_IN; i += 128)
        xs[i >> 6][i & 63] = x[node0 * C_IN + i];
    __syncthreads();
    float acc[8];
    const float bc = b[t];
#pragma unroll
    for (int n = 0; n < 8; ++n) acc[n] = bc;
    for (int k = 0; k < C_IN; ++k) {
        const float w = W[k * C_H + t];
#pragma unroll
        for (int n = 0; n < 8; ++n) acc[n] = fmaf(xs[n][k], w, acc[n]);
    }
#pragma unroll
    for (int n = 0; n < 8; ++n) {
        const float a = acc[n];
        h[(node0 + n) * C_H + t] = a * fast_rcp(1.0f + __expf(-a));
    }
}

// ---------------- edge-parallel gather-aggregate over CSR stream ---------------------------
// block: 128 threads = 2 waves; EBLK=256 edges/block; wave w owns edges [w*128, w*128+128).
// lane l owns channel pair (2l, 2l+1) -> float2 math (v_pk_fma).
// CSR is sorted by col -> run-accumulate; interior segments exclusive -> plain store;
// first/last segment of each wave-chunk -> atomicAdd.
__global__ __launch_bounds__(128) void aggregate_kernel(
        const float2* __restrict__ h2, const float* __restrict__ pos,
        const int2* __restrict__ rc_csr,
        const float* __restrict__ Wc, const float* __restrict__ bc,
        float* __restrict__ agg) {
    __shared__ float rbf_s[EBLK][12];   // 9 used, stride 12 for b128 alignment
    __shared__ int2 rc_s[EBLK];
    const int t = threadIdx.x;
    const int e0 = blockIdx.x * EBLK;
    const int lane = t & 63;
    const int wv = t >> 6;

    // per-lane channel-pair weights
    float2 wc2[D_COUNT];
#pragma unroll
    for (int k = 0; k < D_COUNT; ++k)
        wc2[k] = *(const float2*)&Wc[k * C_H + 2 * lane];
    const float2 bc2 = *(const float2*)&bc[2 * lane];

    // Phase A: 2 edges per thread -> distance + 9 RBFs into LDS
#pragma unroll
    for (int s = 0; s < 2; ++s) {
        const int ei = t + s * 128;
        const int2 rc = rc_csr[e0 + ei];
        rc_s[ei] = rc;
        const float dx = pos[rc.x * 3 + 0] - pos[rc.y * 3 + 0];
        const float dy = pos[rc.x * 3 + 1] - pos[rc.y * 3 + 1];
        const float dz = pos[rc.x * 3 + 2] - pos[rc.y * 3 + 2];
        const float d = sqrtf(dx * dx + dy * dy + dz * dz);
#pragma unroll
        for (int k = 0; k < D_COUNT; ++k) {
            const float u = (d - 0.75f * (float)k) * 1.5f;  // sigma=6/9 -> 1/sigma=1.5
            rbf_s[ei][k] = __expf(-u * u);
        }
    }
    __syncthreads();

    // Phase B: wave-local run-accumulate over 128 CSR edges
    const int jb = wv * 128;
    float2 acc = make_float2(0.0f, 0.0f);
    int cur = rc_s[jb].y;
    bool first = true;
    for (int j = jb; j < jb + 128; ++j) {
        const int2 rc = rc_s[j];          // broadcast LDS read (wave-uniform addr)
        if (rc.y != cur) {                // wave-uniform branch
            float* dst = &agg[(size_t)cur * C_H + 2 * lane];
            if (first) {
                atomicAdd(dst, acc.x);
                atomicAdd(dst + 1, acc.y);
                first = false;
            } else {
                dst[0] = acc.x;
                dst[1] = acc.y;
            }
            acc = make_float2(0.0f, 0.0f);
            cur = rc.y;
        }
        const float4 r0 = *(const float4*)&rbf_s[j][0];
        const float4 r1 = *(const float4*)&rbf_s[j][4];
        const float r8 = rbf_s[j][8];
        float2 a = bc2;
        a.x = fmaf(r0.x, wc2[0].x, a.x); a.y = fmaf(r0.x, wc2[0].y, a.y);
        a.x = fmaf(r0.y, wc2[1].x, a.x); a.y = fmaf(r0.y, wc2[1].y, a.y);
        a.x = fmaf(r0.z, wc2[2].x, a.x); a.y = fmaf(r0.z, wc2[2].y, a.y);
        a.x = fmaf(r0.w, wc2[3].x, a.x); a.y = fmaf(r0.w, wc2[3].y, a.y);
        a.x = fmaf(r1.x, wc2[4].x, a.x); a.y = fmaf(r1.x, wc2[4].y, a.y);
        a.x = fmaf(r1.y, wc2[5].x, a.x); a.y = fmaf(r1.y, wc2[5].y, a.y);
        a.x = fmaf(r1.z, wc2[6].x, a.x); a.y = fmaf(r1.z, wc2[6].y, a.y);
        a.x = fmaf(r1.w, wc2[7].x, a.x); a.y = fmaf(r1.w, wc2[7].y, a.y);
        a.x = fmaf(r8,   wc2[8].x, a.x); a.y = fmaf(r8,   wc2[8].y, a.y);
        float2 sg;
        sg.x = a.x * fast_rcp(1.0f + __expf(-a.x));
        sg.y = a.y * fast_rcp(1.0f + __expf(-a.y));
        // wave-uniform row -> scalar base address
        const int rowu = __builtin_amdgcn_readfirstlane(rc.x);
        const float2 hv = h2[(size_t)rowu * (C_H / 2) + lane];
        acc.x = fmaf(hv.x, sg.x, acc.x);
        acc.y = fmaf(hv.y, sg.y, acc.y);
    }
    // final flush: may continue into next chunk -> atomic
    float* dst = &agg[(size_t)cur * C_H + 2 * lane];
    atomicAdd(dst, acc.x);
    atomicAdd(dst + 1, acc.y);
}

// ---------------- h = g * lrelu((h+agg) @ Wn + bn)/sqrt(1+eps) + be  (in place) -------------
// block: 256 threads = 4 waves, 32 nodes; wave w -> nodes w*8..w*8+8; lane -> channel pair.
__global__ __launch_bounds__(256) void node_kernel(
        float* __restrict__ h, const float* __restrict__ agg,
        const float* __restrict__ Wn, const float* __restrict__ bn,
        const float* __restrict__ g, const float* __restrict__ be) {
    __shared__ float s[32][C_H];
    const int node0 = blockIdx.x * 32;
    const int t = threadIdx.x;
    for (int i = t * 4; i < 32 * C_H; i += 256 * 4) {
        const int n = i >> 7;
        const int c = i & 127;
        if (node0 + n < N_NODES) {
            const float4 hv = *(const float4*)&h[(size_t)(node0 + n) * C_H + c];
            const float4 av = *(const float4*)&agg[(size_t)(node0 + n) * C_H + c];
            float4 r;
            r.x = hv.x + av.x; r.y = hv.y + av.y; r.z = hv.z + av.z; r.w = hv.w + av.w;
            *(float4*)&s[n][c] = r;
        }
    }
    __syncthreads();
    const int wv = t >> 6;
    const int lane = t & 63;
    const int nb = wv * 8;
    const float2 bn2 = *(const float2*)&bn[2 * lane];
    float2 acc[8];
#pragma unroll
    for (int n = 0; n < 8; ++n) acc[n] = bn2;
    for (int k = 0; k < C_H; k += 4) {
        const float2 w0 = *(const float2*)&Wn[(size_t)(k + 0) * C_H + 2 * lane];
        const float2 w1 = *(const float2*)&Wn[(size_t)(k + 1) * C_H + 2 * lane];
        const float2 w2 = *(const float2*)&Wn[(size_t)(k + 2) * C_H + 2 * lane];
        const float2 w3 = *(const float2*)&Wn[(size_t)(k + 3) * C_H + 2 * lane];
#pragma unroll
        for (int n = 0; n < 8; ++n) {
            const float4 sv = *(const float4*)&s[nb + n][k];
            acc[n].x = fmaf(sv.x, w0.x, acc[n].x); acc[n].y = fmaf(sv.x, w0.y, acc[n].y);
            acc[n].x = fmaf(sv.y, w1.x, acc[n].x); acc[n].y = fmaf(sv.y, w1.y, acc[n].y);
            acc[n].x = fmaf(sv.z, w2.x, acc[n].x); acc[n].y = fmaf(sv.z, w2.y, acc[n].y);
            acc[n].x = fmaf(sv.w, w3.x, acc[n].x); acc[n].y = fmaf(sv.w, w3.y, acc[n].y);
        }
    }
    const float inv = 0.9999950000374997f;  // 1/sqrt(1+1e-5)
    float2 g2 = *(const float2*)&g[2 * lane];
    g2.x *= inv; g2.y *= inv;
    const float2 be2 = *(const float2*)&be[2 * lane];
#pragma unroll
    for (int n = 0; n < 8; ++n) {
        const int node = node0 + nb + n;
        if (node < N_NODES) {
            float2 v = acc[n];
            v.x = v.x > 0.0f ? v.x : LRELU_SLOPE * v.x;
            v.y = v.y > 0.0f ? v.y : LRELU_SLOPE * v.y;
            float2 o;
            o.x = fmaf(g2.x, v.x, be2.x);
            o.y = fmaf(g2.y, v.y, be2.y);
            *(float2*)&h[(size_t)node * C_H + 2 * lane] = o;
        }
    }
}

// ---------------- global_add_pool (batch sorted -> run-accumulate) ---------------------------
__global__ void pool_kernel(const float* __restrict__ h, const int* __restrict__ batch,
                            float* __restrict__ out) {
    const int CHUNK = 250;
    const int n0 = blockIdx.x * CHUNK;
    int n1 = n0 + CHUNK;
    if (n1 > N_NODES) n1 = N_NODES;
    const int c = threadIdx.x;
    float acc = 0.0f;
    int curb = batch[n0];
    for (int n = n0; n < n1; ++n) {
        const int bb = batch[n];
        if (bb != curb) {
            atomicAdd(&out[curb * C_H + c], acc);
            acc = 0.0f;
            curb = bb;
        }
        acc += h[n * C_H + c];
    }
    atomicAdd(&out[curb * C_H + c], acc);
}

extern "C" void kernel_launch(void* const* d_in, const int* in_sizes, int n_in,
                              void* d_out, int out_size, void* d_ws, size_t ws_size,
                              hipStream_t stream) {
    const float* x     = (const float*)d_in[0];
    const float* pos   = (const float*)d_in[1];
    const int*   eidx  = (const int*)d_in[2];
    const int*   batch = (const int*)d_in[3];
    const float* W_lin = (const float*)d_in[4];
    const float* b_lin = (const float*)d_in[5];

    float* h   = (float*)d_ws;                           // 6.4M floats
    float* agg = h + (size_t)N_NODES * C_H;              // 6.4M floats
    int* counts  = (int*)(agg + (size_t)N_NODES * C_H);  // 50000
    int* offsets = counts + N_NODES;                     // 50001
    int* cur     = offsets + (N_NODES + 1);              // 50000
    int2* rc_csr = (int2*)(cur + N_NODES + 1);           // 800000 int2

    const int* row = eidx;
    const int* col = eidx + N_EDGES;

    hipMemsetAsync(counts, 0, N_NODES * sizeof(int), stream);
    hipLaunchKernelGGL(hist_kernel, dim3((N_EDGES + 255) / 256), dim3(256), 0, stream,
                       col, counts);
    hipLaunchKernelGGL(scan_kernel, dim3(1), dim3(1024), 0, stream,
                       counts, offsets, cur);
    hipLaunchKernelGGL(scatter_kernel, dim3((N_EDGES + 255) / 256), dim3(256), 0, stream,
                       row, col, cur, rc_csr);

    hipLaunchKernelGGL(lin0_kernel, dim3(N_NODES / 8), dim3(128), 0, stream,
                       x, W_lin, b_lin, h);

    for (int l = 0; l < 3; ++l) {
        const float* Wc = (const float*)d_in[6 + l * 6 + 0];
        const float* bc = (const float*)d_in[6 + l * 6 + 1];
        const float* Wn = (const float*)d_in[6 + l * 6 + 2];
        const float* bn = (const float*)d_in[6 + l * 6 + 3];
        const float* g  = (const float*)d_in[6 + l * 6 + 4];
        const float* be = (const float*)d_in[6 + l * 6 + 5];

        hipMemsetAsync(agg, 0, (size_t)N_NODES * C_H * sizeof(float), stream);
        hipLaunchKernelGGL(aggregate_kernel, dim3(N_EDGES / EBLK), dim3(128), 0, stream,
                           (const float2*)h, pos, rc_csr, Wc, bc, agg);
        hipLaunchKernelGGL(node_kernel, dim3((N_NODES + 31) / 32), dim3(256), 0, stream,
                           h, agg, Wn, bn, g, be);
    }

    hipMemsetAsync(d_out, 0, (size_t)NUM_GRAPHS * C_H * sizeof(float), stream);
    hipLaunchKernelGGL(pool_kernel, dim3((N_NODES + 249) / 250), dim3(128), 0, stream,
                       h, batch, (float*)d_out);
}

// Round 4
// 624.097 us; speedup vs baseline: 1.2016x; 1.2016x over previous
//
#include <hip/hip_runtime.h>
#include <math.h>

#define N_NODES 50000
#define N_EDGES 800000
#define NUM_GRAPHS 256
#define C_IN 64
#define C_H 128
#define D_COUNT 9
#define LRELU_SLOPE 0.01f
#define BN_EPS 1e-5f
#define EBLK 256
#define SCAN_BLK ((N_NODES + 255) / 256)   // 196

__device__ __forceinline__ float fast_rcp(float x) { return __builtin_amdgcn_rcpf(x); }

// ---------------- CSR build (once; edge structure shared by all 3 layers) ------------------

__global__ void hist_kernel(const int* __restrict__ col, int* __restrict__ counts) {
    const int e = blockIdx.x * 256 + threadIdx.x;
    if (e < N_EDGES) atomicAdd(&counts[col[e]], 1);
}

// stage A: per-block exclusive scan of 256 counts; emit block totals
__global__ void scan_a(const int* __restrict__ counts, int* __restrict__ curp,
                       int* __restrict__ blocksums) {
    __shared__ int s[256];
    const int t = threadIdx.x;
    const int i = blockIdx.x * 256 + t;
    const int v = (i < N_NODES) ? counts[i] : 0;
    s[t] = v;
    __syncthreads();
    for (int d = 1; d < 256; d <<= 1) {
        const int x = (t >= d) ? s[t - d] : 0;
        __syncthreads();
        s[t] += x;
        __syncthreads();
    }
    if (i < N_NODES) curp[i] = s[t] - v;  // exclusive within block
    if (t == 255) blocksums[blockIdx.x] = s[255];
}

// stage B: scan the 196 block sums (single small block)
__global__ void scan_b(int* __restrict__ blocksums) {
    __shared__ int s[256];
    const int t = threadIdx.x;
    const int v = (t < SCAN_BLK) ? blocksums[t] : 0;
    s[t] = v;
    __syncthreads();
    for (int d = 1; d < 256; d <<= 1) {
        const int x = (t >= d) ? s[t - d] : 0;
        __syncthreads();
        s[t] += x;
        __syncthreads();
    }
    if (t < SCAN_BLK) blocksums[t] = s[t] - v;  // exclusive
}

// stage C: add block prefix -> final exclusive scan in curp
__global__ void scan_c(int* __restrict__ curp, const int* __restrict__ blocksums) {
    const int i = blockIdx.x * 256 + threadIdx.x;
    if (i < N_NODES) curp[i] += blocksums[blockIdx.x];
}

__global__ void scatter_kernel(const int* __restrict__ row, const int* __restrict__ col,
                               int* __restrict__ cur, int2* __restrict__ rc_csr) {
    const int e = blockIdx.x * 256 + threadIdx.x;
    if (e < N_EDGES) {
        const int cl = col[e];
        const int p = atomicAdd(&cur[cl], 1);
        rc_csr[p] = make_int2(row[e], cl);
    }
}

// ---------------- h = silu(x @ W_lin + b_lin) ----------------------------------------------
__global__ void lin0_kernel(const float* __restrict__ x, const float* __restrict__ W,
                            const float* __restrict__ b, float* __restrict__ h) {
    __shared__ float xs[8][C_IN];
    const int node0 = blockIdx.x * 8;
    const int t = threadIdx.x;
    for (int i = t; i < 8 * C_IN; i += 128)
        xs[i >> 6][i & 63] = x[node0 * C_IN + i];
    __syncthreads();
    float acc[8];
    const float bc = b[t];
#pragma unroll
    for (int n = 0; n < 8; ++n) acc[n] = bc;
    for (int k = 0; k < C_IN; ++k) {
        const float w = W[k * C_H + t];
#pragma unroll
        for (int n = 0; n < 8; ++n) acc[n] = fmaf(xs[n][k], w, acc[n]);
    }
#pragma unroll
    for (int n = 0; n < 8; ++n) {
        const float a = acc[n];
        h[(node0 + n) * C_H + t] = a * fast_rcp(1.0f + __expf(-a));
    }
}

// ---------------- edge-parallel gather-aggregate over CSR stream ---------------------------
// block: 128 threads = 2 waves; EBLK=256 edges/block; wave w owns edges [w*128, w*128+128).
// lane l owns channel pair (2l, 2l+1) -> float2 (v_pk_fma). CSR sorted by col ->
// run-accumulate; interior segments block-exclusive -> plain store; boundary -> atomicAdd.
// 1-deep software prefetch of next edge's (rc, h-row) hides gather latency under FMA chain.
__global__ __launch_bounds__(128) void aggregate_kernel(
        const float2* __restrict__ h2, const float* __restrict__ pos,
        const int2* __restrict__ rc_csr,
        const float* __restrict__ Wc, const float* __restrict__ bc,
        float* __restrict__ agg) {
    __shared__ float rbf_s[EBLK][12];   // 9 used; stride 12 keeps b128 alignment
    __shared__ int2 rc_s[EBLK];
    const int t = threadIdx.x;
    const int e0 = blockIdx.x * EBLK;
    const int lane = t & 63;
    const int wv = t >> 6;

    float2 wc2[D_COUNT];
#pragma unroll
    for (int k = 0; k < D_COUNT; ++k)
        wc2[k] = *(const float2*)&Wc[k * C_H + 2 * lane];
    const float2 bc2 = *(const float2*)&bc[2 * lane];

    // Phase A: 2 edges per thread -> distance + 9 RBFs into LDS
#pragma unroll
    for (int s = 0; s < 2; ++s) {
        const int ei = t + s * 128;
        const int2 rc = rc_csr[e0 + ei];
        rc_s[ei] = rc;
        const float dx = pos[rc.x * 3 + 0] - pos[rc.y * 3 + 0];
        const float dy = pos[rc.x * 3 + 1] - pos[rc.y * 3 + 1];
        const float dz = pos[rc.x * 3 + 2] - pos[rc.y * 3 + 2];
        const float d = sqrtf(dx * dx + dy * dy + dz * dz);
#pragma unroll
        for (int k = 0; k < D_COUNT; ++k) {
            const float u = (d - 0.75f * (float)k) * 1.5f;  // sigma=6/9 -> 1/sigma=1.5
            rbf_s[ei][k] = __expf(-u * u);
        }
    }
    __syncthreads();

    // Phase B: wave-local run-accumulate with 1-deep prefetch
    const int jb = wv * 128;
    int2 rc = rc_s[jb];
    float2 hv = h2[(size_t)__builtin_amdgcn_readfirstlane(rc.x) * (C_H / 2) + lane];
    float2 acc = make_float2(0.0f, 0.0f);
    bool first = true;

    for (int j = jb; j < jb + 127; ++j) {
        // prefetch next edge
        const int2 rc_n = rc_s[j + 1];
        const float2 hv_n = h2[(size_t)__builtin_amdgcn_readfirstlane(rc_n.x) * (C_H / 2) + lane];
        // compute current edge
        const float4 r0 = *(const float4*)&rbf_s[j][0];
        const float4 r1 = *(const float4*)&rbf_s[j][4];
        const float r8 = rbf_s[j][8];
        float2 a = bc2;
        a.x = fmaf(r0.x, wc2[0].x, a.x); a.y = fmaf(r0.x, wc2[0].y, a.y);
        a.x = fmaf(r0.y, wc2[1].x, a.x); a.y = fmaf(r0.y, wc2[1].y, a.y);
        a.x = fmaf(r0.z, wc2[2].x, a.x); a.y = fmaf(r0.z, wc2[2].y, a.y);
        a.x = fmaf(r0.w, wc2[3].x, a.x); a.y = fmaf(r0.w, wc2[3].y, a.y);
        a.x = fmaf(r1.x, wc2[4].x, a.x); a.y = fmaf(r1.x, wc2[4].y, a.y);
        a.x = fmaf(r1.y, wc2[5].x, a.x); a.y = fmaf(r1.y, wc2[5].y, a.y);
        a.x = fmaf(r1.z, wc2[6].x, a.x); a.y = fmaf(r1.z, wc2[6].y, a.y);
        a.x = fmaf(r1.w, wc2[7].x, a.x); a.y = fmaf(r1.w, wc2[7].y, a.y);
        a.x = fmaf(r8,   wc2[8].x, a.x); a.y = fmaf(r8,   wc2[8].y, a.y);
        float2 sg;
        sg.x = a.x * fast_rcp(1.0f + __expf(-a.x));
        sg.y = a.y * fast_rcp(1.0f + __expf(-a.y));
        acc.x = fmaf(hv.x, sg.x, acc.x);
        acc.y = fmaf(hv.y, sg.y, acc.y);
        // segment boundary? (wave-uniform)
        if (rc_n.y != rc.y) {
            float* dst = &agg[(size_t)rc.y * C_H + 2 * lane];
            if (first) {
                atomicAdd(dst, acc.x);
                atomicAdd(dst + 1, acc.y);
                first = false;
            } else {
                dst[0] = acc.x;
                dst[1] = acc.y;
            }
            acc = make_float2(0.0f, 0.0f);
        }
        rc = rc_n;
        hv = hv_n;
    }
    // last edge
    {
        const int j = jb + 127;
        const float4 r0 = *(const float4*)&rbf_s[j][0];
        const float4 r1 = *(const float4*)&rbf_s[j][4];
        const float r8 = rbf_s[j][8];
        float2 a = bc2;
        a.x = fmaf(r0.x, wc2[0].x, a.x); a.y = fmaf(r0.x, wc2[0].y, a.y);
        a.x = fmaf(r0.y, wc2[1].x, a.x); a.y = fmaf(r0.y, wc2[1].y, a.y);
        a.x = fmaf(r0.z, wc2[2].x, a.x); a.y = fmaf(r0.z, wc2[2].y, a.y);
        a.x = fmaf(r0.w, wc2[3].x, a.x); a.y = fmaf(r0.w, wc2[3].y, a.y);
        a.x = fmaf(r1.x, wc2[4].x, a.x); a.y = fmaf(r1.x, wc2[4].y, a.y);
        a.x = fmaf(r1.y, wc2[5].x, a.x); a.y = fmaf(r1.y, wc2[5].y, a.y);
        a.x = fmaf(r1.z, wc2[6].x, a.x); a.y = fmaf(r1.z, wc2[6].y, a.y);
        a.x = fmaf(r1.w, wc2[7].x, a.x); a.y = fmaf(r1.w, wc2[7].y, a.y);
        a.x = fmaf(r8,   wc2[8].x, a.x); a.y = fmaf(r8,   wc2[8].y, a.y);
        float2 sg;
        sg.x = a.x * fast_rcp(1.0f + __expf(-a.x));
        sg.y = a.y * fast_rcp(1.0f + __expf(-a.y));
        acc.x = fmaf(hv.x, sg.x, acc.x);
        acc.y = fmaf(hv.y, sg.y, acc.y);
        float* dst = &agg[(size_t)rc.y * C_H + 2 * lane];
        atomicAdd(dst, acc.x);
        atomicAdd(dst + 1, acc.y);
    }
}

// ---------------- h = g * lrelu((h+agg) @ Wn + bn)/sqrt(1+eps) + be  (in place) -------------
__global__ __launch_bounds__(256) void node_kernel(
        float* __restrict__ h, const float* __restrict__ agg,
        const float* __restrict__ Wn, const float* __restrict__ bn,
        const float* __restrict__ g, const float* __restrict__ be) {
    __shared__ float s[32][C_H];
    const int node0 = blockIdx.x * 32;
    const int t = threadIdx.x;
    for (int i = t * 4; i < 32 * C_H; i += 256 * 4) {
        const int n = i >> 7;
        const int c = i & 127;
        if (node0 + n < N_NODES) {
            const float4 hv = *(const float4*)&h[(size_t)(node0 + n) * C_H + c];
            const float4 av = *(const float4*)&agg[(size_t)(node0 + n) * C_H + c];
            float4 r;
            r.x = hv.x + av.x; r.y = hv.y + av.y; r.z = hv.z + av.z; r.w = hv.w + av.w;
            *(float4*)&s[n][c] = r;
        }
    }
    __syncthreads();
    const int wv = t >> 6;
    const int lane = t & 63;
    const int nb = wv * 8;
    const float2 bn2 = *(const float2*)&bn[2 * lane];
    float2 acc[8];
#pragma unroll
    for (int n = 0; n < 8; ++n) acc[n] = bn2;
    for (int k = 0; k < C_H; k += 4) {
        const float2 w0 = *(const float2*)&Wn[(size_t)(k + 0) * C_H + 2 * lane];
        const float2 w1 = *(const float2*)&Wn[(size_t)(k + 1) * C_H + 2 * lane];
        const float2 w2 = *(const float2*)&Wn[(size_t)(k + 2) * C_H + 2 * lane];
        const float2 w3 = *(const float2*)&Wn[(size_t)(k + 3) * C_H + 2 * lane];
#pragma unroll
        for (int n = 0; n < 8; ++n) {
            const float4 sv = *(const float4*)&s[nb + n][k];
            acc[n].x = fmaf(sv.x, w0.x, acc[n].x); acc[n].y = fmaf(sv.x, w0.y, acc[n].y);
            acc[n].x = fmaf(sv.y, w1.x, acc[n].x); acc[n].y = fmaf(sv.y, w1.y, acc[n].y);
            acc[n].x = fmaf(sv.z, w2.x, acc[n].x); acc[n].y = fmaf(sv.z, w2.y, acc[n].y);
            acc[n].x = fmaf(sv.w, w3.x, acc[n].x); acc[n].y = fmaf(sv.w, w3.y, acc[n].y);
        }
    }
    const float inv = 0.9999950000374997f;  // 1/sqrt(1+1e-5)
    float2 g2 = *(const float2*)&g[2 * lane];
    g2.x *= inv; g2.y *= inv;
    const float2 be2 = *(const float2*)&be[2 * lane];
#pragma unroll
    for (int n = 0; n < 8; ++n) {
        const int node = node0 + nb + n;
        if (node < N_NODES) {
            float2 v = acc[n];
            v.x = v.x > 0.0f ? v.x : LRELU_SLOPE * v.x;
            v.y = v.y > 0.0f ? v.y : LRELU_SLOPE * v.y;
            float2 o;
            o.x = fmaf(g2.x, v.x, be2.x);
            o.y = fmaf(g2.y, v.y, be2.y);
            *(float2*)&h[(size_t)node * C_H + 2 * lane] = o;
        }
    }
}

// ---------------- global_add_pool (batch sorted -> run-accumulate) ---------------------------
__global__ void pool_kernel(const float* __restrict__ h, const int* __restrict__ batch,
                            float* __restrict__ out) {
    const int CHUNK = 250;
    const int n0 = blockIdx.x * CHUNK;
    int n1 = n0 + CHUNK;
    if (n1 > N_NODES) n1 = N_NODES;
    const int c = threadIdx.x;
    float acc = 0.0f;
    int curb = batch[n0];
    for (int n = n0; n < n1; ++n) {
        const int bb = batch[n];
        if (bb != curb) {
            atomicAdd(&out[curb * C_H + c], acc);
            acc = 0.0f;
            curb = bb;
        }
        acc += h[n * C_H + c];
    }
    atomicAdd(&out[curb * C_H + c], acc);
}

extern "C" void kernel_launch(void* const* d_in, const int* in_sizes, int n_in,
                              void* d_out, int out_size, void* d_ws, size_t ws_size,
                              hipStream_t stream) {
    const float* x     = (const float*)d_in[0];
    const float* pos   = (const float*)d_in[1];
    const int*   eidx  = (const int*)d_in[2];
    const int*   batch = (const int*)d_in[3];
    const float* W_lin = (const float*)d_in[4];
    const float* b_lin = (const float*)d_in[5];

    float* h   = (float*)d_ws;                            // 6,400,000 f
    float* agg = h + (size_t)N_NODES * C_H;               // 6,400,000 f
    int* counts    = (int*)(agg + (size_t)N_NODES * C_H); // 50,000
    int* curp      = counts + N_NODES;                    // 50,000
    int* blocksums = curp + N_NODES;                      // 256
    int2* rc_csr   = (int2*)(blocksums + 256);            // 800,000 int2 (8B-aligned)

    const int* row = eidx;
    const int* col = eidx + N_EDGES;

    // CSR build
    hipMemsetAsync(counts, 0, N_NODES * sizeof(int), stream);
    hipLaunchKernelGGL(hist_kernel, dim3((N_EDGES + 255) / 256), dim3(256), 0, stream,
                       col, counts);
    hipLaunchKernelGGL(scan_a, dim3(SCAN_BLK), dim3(256), 0, stream,
                       counts, curp, blocksums);
    hipLaunchKernelGGL(scan_b, dim3(1), dim3(256), 0, stream, blocksums);
    hipLaunchKernelGGL(scan_c, dim3(SCAN_BLK), dim3(256), 0, stream, curp, blocksums);
    hipLaunchKernelGGL(scatter_kernel, dim3((N_EDGES + 255) / 256), dim3(256), 0, stream,
                       row, col, curp, rc_csr);

    hipLaunchKernelGGL(lin0_kernel, dim3(N_NODES / 8), dim3(128), 0, stream,
                       x, W_lin, b_lin, h);

    for (int l = 0; l < 3; ++l) {
        const float* Wc = (const float*)d_in[6 + l * 6 + 0];
        const float* bc = (const float*)d_in[6 + l * 6 + 1];
        const float* Wn = (const float*)d_in[6 + l * 6 + 2];
        const float* bn = (const float*)d_in[6 + l * 6 + 3];
        const float* g  = (const float*)d_in[6 + l * 6 + 4];
        const float* be = (const float*)d_in[6 + l * 6 + 5];

        hipMemsetAsync(agg, 0, (size_t)N_NODES * C_H * sizeof(float), stream);
        hipLaunchKernelGGL(aggregate_kernel, dim3(N_EDGES / EBLK), dim3(128), 0, stream,
                           (const float2*)h, pos, rc_csr, Wc, bc, agg);
        hipLaunchKernelGGL(node_kernel, dim3((N_NODES + 31) / 32), dim3(256), 0, stream,
                           h, agg, Wn, bn, g, be);
    }

    hipMemsetAsync(d_out, 0, (size_t)NUM_GRAPHS * C_H * sizeof(float), stream);
    hipLaunchKernelGGL(pool_kernel, dim3((N_NODES + 249) / 250), dim3(128), 0, stream,
                       h, batch, (float*)d_out);
}